// Round 5
// baseline (895.797 us; speedup 1.0000x reference)
//
#include <hip/hip_runtime.h>
#include <hip/hip_bf16.h>
#include <hip/hip_fp16.h>

// Problem constants: B=16, C=256, N=2048, NUM_SA=4
static constexpr int Bn = 16;
static constexpr int Cc = 256;
static constexpr int Nn = 2048;
static constexpr int C4 = 64;
static constexpr float LOG2E = 1.4426950408889634f;

typedef _Float16 half_t;
typedef __attribute__((ext_vector_type(8))) _Float16 half8;
typedef __attribute__((ext_vector_type(4))) _Float16 half4;
typedef __attribute__((ext_vector_type(8))) short short8;
typedef __attribute__((ext_vector_type(4))) float float4v;

static constexpr long sNC = (long)Nn * Cc;   // 524288
static constexpr long sNQ = (long)Nn * C4;   // 131072

#define DEVI __device__ __forceinline__

DEVI float bf2f(unsigned short u) { return __uint_as_float(((unsigned)u) << 16); }
DEVI unsigned short f2bf(float f) {
    unsigned x = __float_as_uint(f);
    x += 0x7fffu + ((x >> 16) & 1u);   // RNE
    return (unsigned short)(x >> 16);
}

// async global->LDS, 16B per lane. LDS dest = wave-uniform base + lane*16.
DEVI void gload16(const void* g, void* l) {
    __builtin_amdgcn_global_load_lds(
        (const __attribute__((address_space(1))) unsigned int*)g,
        (__attribute__((address_space(3))) unsigned int*)l, 16, 0, 0);
}

enum { EPI_RAW = 0, EPI_H = 1, EPI_XV = 2 };

// Canonical MFMA GEMM: Y[j][i] = epi( sum_k A[i*K+k] * B[j*K+k] )
// NW = WI*WJ waves (NW*64 threads). Wave (wi = w%WI, wj = w/WI) owns a
// 64x64 output tile.
template<int MODE, int BM, int BN, int WI, int WJ, bool BF16OUT>
__global__ __launch_bounds__(WI * WJ * 64)
void mgemm(const half_t* __restrict__ A, long aB,
           const half_t* __restrict__ Bm, long bB,
           void* __restrict__ Yv, long yB, int ldy,
           const float* __restrict__ bias,
           const float* __restrict__ bng, const float* __restrict__ bnb,
           const float* __restrict__ bnm, const float* __restrict__ bnv,
           int K)
{
    constexpr int NW = WI * WJ;
    __shared__ __align__(16) half_t Als[2][BM][32];
    __shared__ __align__(16) half_t Bls[2][BN][32];

    const int tid  = threadIdx.x;
    const int w    = tid >> 6;
    const int lane = tid & 63;
    const int wi   = w % WI;
    const int wj   = w / WI;
    const int quad = lane >> 4, m16 = lane & 15;
    const int lr   = lane >> 2, lc = lane & 3;
    const int b    = blockIdx.z;
    const int j0   = blockIdx.x * BN;
    const int i0   = blockIdx.y * BM;

    const half_t* Ab = A + (size_t)b * aB;
    const half_t* Bb = Bm + (size_t)b * bB;

    float4v acc[4][4];
    #pragma unroll
    for (int i = 0; i < 4; ++i)
        #pragma unroll
        for (int j = 0; j < 4; ++j) acc[i][j] = (float4v)0.f;

    for (int k0 = 0; k0 < K; k0 += 64) {
        #pragma unroll
        for (int s = 0; s < 2; ++s) {
            const int kk = k0 + s * 32 + lc * 8;
            #pragma unroll
            for (int t = 0; t < BM / (16 * NW); ++t) {
                const int row = (t * NW + w) * 16;
                gload16(Ab + (size_t)(i0 + row + lr) * K + kk, &Als[s][row][0]);
            }
            #pragma unroll
            for (int t = 0; t < BN / (16 * NW); ++t) {
                const int row = (t * NW + w) * 16;
                gload16(Bb + (size_t)(j0 + row + lr) * K + kk, &Bls[s][row][0]);
            }
        }
        __syncthreads();
        #pragma unroll
        for (int s = 0; s < 2; ++s) {
            half8 af[4], bf[4];
            #pragma unroll
            for (int t = 0; t < 4; ++t)
                af[t] = *(const half8*)&Als[s][wi * 64 + t * 16 + m16][quad * 8];
            #pragma unroll
            for (int t = 0; t < 4; ++t)
                bf[t] = *(const half8*)&Bls[s][wj * 64 + t * 16 + m16][quad * 8];
            #pragma unroll
            for (int ti = 0; ti < 4; ++ti)
                #pragma unroll
                for (int tj = 0; tj < 4; ++tj)
                    acc[ti][tj] = __builtin_amdgcn_mfma_f32_16x16x32_f16(
                        af[ti], bf[tj], acc[ti][tj], 0, 0, 0);
        }
        __syncthreads();
    }

    #pragma unroll
    for (int ti = 0; ti < 4; ++ti) {
        const int il = i0 + wi * 64 + ti * 16 + quad * 4;
        #pragma unroll
        for (int tj = 0; tj < 4; ++tj) {
            const int jl = j0 + wj * 64 + tj * 16 + m16;
            float4v v = acc[ti][tj];
            if (MODE == EPI_RAW) {
                half4 o;
                #pragma unroll
                for (int r = 0; r < 4; ++r) o[r] = (half_t)v[r];
                *(half4*)((half_t*)Yv + (size_t)b * yB + (size_t)jl * ldy + il) = o;
            } else if (MODE == EPI_H) {
                half4 o;
                #pragma unroll
                for (int r = 0; r < 4; ++r) {
                    const float sc = bng[il + r] * rsqrtf(bnv[il + r] + 1e-3f);
                    const float sh = bnb[il + r] - bnm[il + r] * sc;
                    o[r] = (half_t)fmaxf(fmaf(v[r], sc, sh), 0.f);
                }
                *(half4*)((half_t*)Yv + (size_t)b * yB + (size_t)jl * ldy + il) = o;
            } else {   // EPI_XV
                const float bj = bias[jl];
                if (BF16OUT) {
                    ushort4 o;
                    o.x = f2bf(v[0] + bj); o.y = f2bf(v[1] + bj);
                    o.z = f2bf(v[2] + bj); o.w = f2bf(v[3] + bj);
                    *(ushort4*)((unsigned short*)Yv + (size_t)b * yB + (size_t)jl * ldy + il) = o;
                } else {
                    half4 o;
                    #pragma unroll
                    for (int r = 0; r < 4; ++r) o[r] = (half_t)(v[r] + bj);
                    *(half4*)((half_t*)Yv + (size_t)b * yB + (size_t)jl * ldy + il) = o;
                }
            }
        }
    }
}

// Pass 1: E = q q^T tile (i=n rows, j=m cols, K=64), NO E store.
// Per-block per-column (max, sumexp) partials -> Pbuf[b][m][16 iblk][2].
__global__ __launch_bounds__(256)
void estats(const half_t* __restrict__ q, float* __restrict__ Pbuf)
{
    __shared__ __align__(16) half_t sA[128 * 64];
    __shared__ __align__(16) half_t sB[128 * 64];
    __shared__ float red[2][2][4][16][2];
    const int tid = threadIdx.x, w = tid >> 6, lane = tid & 63;
    const int wi = w & 1, wj = w >> 1, quad = lane >> 4, m16 = lane & 15;
    const int b = blockIdx.z, j0 = blockIdx.x * 128, i0 = blockIdx.y * 128;
    const half_t* qb = q + (size_t)b * sNQ;

    #pragma unroll
    for (int t = 0; t < 4; ++t) {
        const int g = w * 256 + t * 64 + lane;
        const int r = g >> 3, c = g & 7;
        const int cs = c ^ (r & 7);
        gload16(qb + (size_t)(i0 + r) * 64 + cs * 8, sA + (w * 256 + t * 64) * 8);
        gload16(qb + (size_t)(j0 + r) * 64 + cs * 8, sB + (w * 256 + t * 64) * 8);
    }
    __syncthreads();

    half8 an[4][2], bm[4][2];
    #pragma unroll
    for (int t = 0; t < 4; ++t)
        #pragma unroll
        for (int ks = 0; ks < 2; ++ks) {
            const int pc = ((ks * 4 + quad) ^ (m16 & 7)) * 8;
            an[t][ks] = *(const half8*)&sA[(wi * 64 + t * 16 + m16) * 64 + pc];
            bm[t][ks] = *(const half8*)&sB[(wj * 64 + t * 16 + m16) * 64 + pc];
        }

    #pragma unroll
    for (int tj = 0; tj < 4; ++tj) {
        float4v e[4];
        #pragma unroll
        for (int ti = 0; ti < 4; ++ti) {
            e[ti] = (float4v)0.f;
            e[ti] = __builtin_amdgcn_mfma_f32_16x16x32_f16(an[ti][0], bm[tj][0], e[ti], 0, 0, 0);
            e[ti] = __builtin_amdgcn_mfma_f32_16x16x32_f16(an[ti][1], bm[tj][1], e[ti], 0, 0, 0);
        }
        float lmax = -1e30f;
        #pragma unroll
        for (int ti = 0; ti < 4; ++ti)
            #pragma unroll
            for (int r = 0; r < 4; ++r) lmax = fmaxf(lmax, e[ti][r]);
        lmax = fmaxf(lmax, __shfl_xor(lmax, 16));
        lmax = fmaxf(lmax, __shfl_xor(lmax, 32));
        float ls = 0.f;
        #pragma unroll
        for (int ti = 0; ti < 4; ++ti)
            #pragma unroll
            for (int r = 0; r < 4; ++r) ls += __expf(e[ti][r] - lmax);
        ls += __shfl_xor(ls, 16);
        ls += __shfl_xor(ls, 32);
        if (quad == 0) { red[wi][wj][tj][m16][0] = lmax; red[wi][wj][tj][m16][1] = ls; }
    }
    __syncthreads();
    if (tid < 128) {
        const int wj2 = tid >> 6, tj2 = (tid >> 4) & 3, mm = tid & 15;
        const float m0 = red[0][wj2][tj2][mm][0], s0 = red[0][wj2][tj2][mm][1];
        const float m1 = red[1][wj2][tj2][mm][0], s1 = red[1][wj2][tj2][mm][1];
        const float M = fmaxf(m0, m1);
        const float S = s0 * __expf(m0 - M) + s1 * __expf(m1 - M);
        const int m = j0 + wj2 * 64 + tj2 * 16 + mm;
        *(float2*)(Pbuf + (((size_t)b * Nn + m) * 16 + blockIdx.y) * 2) = make_float2(M, S);
    }
}

// Pass 2: fused attention-apply + t-GEMM + bn/relu/residual epilogue.
// 1024 threads (16 waves), 1 block per (b, m-tile), XCD-aware mapping.
// Software-pipelined main loop (32 chunks of 64 n):
//   chunk nc: [load E A-frags (global, L2-hot) | issue sXV[next] stage]
//             -> E (MFMA+exp+pack -> sP) -> raw barrier (lgkmcnt only,
//             stage loads stay IN FLIGHT) -> XR MFMAs -> raw barrier.
// The compiler's own wait for the A-frag registers is vmcnt(2) (2 younger
// stage loads outstanding), which transitively drains the PREVIOUS chunk's
// stage -> sXV[cur] is guaranteed landed at the first barrier without ever
// executing vmcnt(0) in the loop. q (256 KB/batch) is XCD-L2-resident after
// the swizzle, so E A-frags and bq are direct per-lane global loads (no sQ).
// LDS: sXV 2x32 + sP 16 + sOff 8 = 88 KB.
__global__ __launch_bounds__(1024)
void flashxr(const half_t* __restrict__ q, const half_t* __restrict__ xv,
             const half_t* __restrict__ h, const float* __restrict__ Pbuf,
             const half_t* __restrict__ tw, const float* __restrict__ tb,
             const float* __restrict__ bng, const float* __restrict__ bnb,
             const float* __restrict__ bnm, const float* __restrict__ bnv,
             float* __restrict__ outL, half_t* __restrict__ hNext)
{
    __shared__ __align__(16) half_t sXV[2][256 * 64];  // 64 KB, double-buffered
    __shared__ __align__(16) half_t sP[128 * 64];      // 16 KB: P tile / cs buf
    __shared__ float sOff[Nn];                         // 8 KB

    const int tid = threadIdx.x, w = tid >> 6, lane = tid & 63;
    const int quad = lane >> 4, m16 = lane & 15;
    const int wiE = w & 1, wjE = w >> 1;        // E: n-32-half, m-16-tile (8)
    const int wi = w & 3, wj = w >> 2;          // XR: c-64-tile, m-32-tile
    const int wiT = w & 1, wjT = w >> 1;        // T: m-half, co-32-tile
    // XCD-aware (b, j0) assignment from 1-D block id (XCD = bid % 8)
    const int f = blockIdx.x;
    const int W = (f & 7) * 32 + (f >> 3);
    const int b = W >> 4, j0 = (W & 15) * 128;
    const half_t* qb  = q + (size_t)b * sNQ;
    const half_t* xvb = xv + (size_t)b * sNC;   // [256][2048] bf16 bits

    // ---- prologue ----
    // stage chunk 0 into sXV[0] (latency hides under statsreduce)
    #pragma unroll
    for (int t = 0; t < 2; ++t) {
        const int g = t * 1024 + tid;
        const int r = g >> 3, c = g & 7;
        gload16(xvb + (size_t)r * Nn + ((c ^ (r & 7)) * 8), &sXV[0][(size_t)g * 8]);
    }
    __builtin_amdgcn_sched_barrier(0);

    // bq: B-operand fragments for this wave's m-16-tile, direct from L2
    half8 bq[2];
    #pragma unroll
    for (int s = 0; s < 2; ++s)
        bq[s] = *(const half8*)(qb + (size_t)(j0 + wjE * 16 + m16) * 64 + (s * 4 + quad) * 8);

    {   // statsreduce: off[n] = M*log2e + log2(S) from 16 per-block partials
        const float* pB = Pbuf + (size_t)b * Nn * 32;
        for (int i = tid; i < Nn; i += 1024) {
            const float4v* p4 = (const float4v*)(pB + (size_t)i * 32);
            float4v v[8];
            #pragma unroll
            for (int t = 0; t < 8; ++t) v[t] = p4[t];
            float M = -1e30f;
            #pragma unroll
            for (int t = 0; t < 8; ++t) { M = fmaxf(M, v[t][0]); M = fmaxf(M, v[t][2]); }
            float S = 0.f;
            #pragma unroll
            for (int t = 0; t < 8; ++t) {
                S += v[t][1] * __expf(v[t][0] - M);
                S += v[t][3] * __expf(v[t][2] - M);
            }
            sOff[i] = fmaf(M, LOG2E, __log2f(S));
        }
    }
    asm volatile("s_waitcnt lgkmcnt(0)" ::: "memory");
    __builtin_amdgcn_s_barrier();
    __builtin_amdgcn_sched_barrier(0);

    float4v acc[4][2];
    #pragma unroll
    for (int i = 0; i < 4; ++i)
        #pragma unroll
        for (int j = 0; j < 2; ++j) acc[i][j] = (float4v)0.f;
    float csa = 0.f;

    const int mrow = wjE * 16 + m16;

    for (int nc = 0; nc < 32; ++nc) {
        const int cur = nc & 1;

        // E A-fragments: direct per-lane global loads (issued FIRST: oldest)
        half8 an[2][2];
        #pragma unroll
        for (int ti = 0; ti < 2; ++ti)
            #pragma unroll
            for (int s = 0; s < 2; ++s)
                an[ti][s] = *(const half8*)(qb
                    + (size_t)(nc * 64 + wiE * 32 + ti * 16 + m16) * 64
                    + (s * 4 + quad) * 8);
        __builtin_amdgcn_sched_barrier(0);

        // stage NEXT chunk into the other buffer (stays in flight across
        // both barriers; consumed by XR one full chunk from now)
        if (nc < 31) {
            #pragma unroll
            for (int t = 0; t < 2; ++t) {
                const int g = t * 1024 + tid;
                const int r = g >> 3, c = g & 7;
                gload16(xvb + (size_t)r * Nn + (nc + 1) * 64 + ((c ^ (r & 7)) * 8),
                        &sXV[cur ^ 1][(size_t)g * 8]);
            }
        }
        __builtin_amdgcn_sched_barrier(0);

        // E phase: 2 n-16-tiles per wave; compiler waits vmcnt(2) for an[]
        #pragma unroll
        for (int ti = 0; ti < 2; ++ti) {
            float4v e = (float4v)0.f;
            e = __builtin_amdgcn_mfma_f32_16x16x32_f16(an[ti][0], bq[0], e, 0, 0, 0);
            e = __builtin_amdgcn_mfma_f32_16x16x32_f16(an[ti][1], bq[1], e, 0, 0, 0);
            const float4v o4 = *(const float4v*)&sOff[nc * 64 + wiE * 32 + ti * 16 + quad * 4];
            float c0 = 0.f; ushort4 pk;
            #pragma unroll
            for (int r = 0; r < 4; ++r) {
                const float p = __builtin_amdgcn_exp2f(fmaf(e[r], LOG2E, -o4[r]));
                c0 += p; (&pk.x)[r] = f2bf(p);
            }
            csa += c0;
            const int pc = (wiE * 4 + ti * 2 + (quad >> 1)) ^ (m16 & 7);
            *(ushort4*)&((unsigned short*)sP)[(size_t)mrow * 64 + pc * 8 + (quad & 1) * 4] = pk;
        }
        // B1: publish sP; sXV[cur] already drained via the an[] vmcnt wait.
        // NO vmcnt here -> next-chunk stage stays in flight.
        asm volatile("s_waitcnt lgkmcnt(0)" ::: "memory");
        __builtin_amdgcn_s_barrier();
        __builtin_amdgcn_sched_barrier(0);

        // XR phase: acc[c][m] += xv[c][k=n] * P[m][k=n], K = 64
        #pragma unroll
        for (int ks = 0; ks < 2; ++ks) {
            short8 xa[4], pb[2];
            #pragma unroll
            for (int ti = 0; ti < 4; ++ti)
                xa[ti] = *(const short8*)&sXV[cur][(size_t)(wi * 64 + ti * 16 + m16) * 64
                                                  + (((ks * 4 + quad) ^ (m16 & 7)) * 8)];
            #pragma unroll
            for (int tj = 0; tj < 2; ++tj)
                pb[tj] = *(const short8*)&sP[(size_t)(wj * 32 + tj * 16 + m16) * 64
                                             + (((ks * 4 + quad) ^ (m16 & 7)) * 8)];
            __builtin_amdgcn_s_setprio(1);
            #pragma unroll
            for (int ti = 0; ti < 4; ++ti)
                #pragma unroll
                for (int tj = 0; tj < 2; ++tj)
                    acc[ti][tj] = __builtin_amdgcn_mfma_f32_16x16x32_bf16(
                        xa[ti], pb[tj], acc[ti][tj], 0, 0, 0);
            __builtin_amdgcn_s_setprio(0);
        }
        // B2: XR reads done before next chunk overwrites sP / stages sXV[cur]
        asm volatile("s_waitcnt lgkmcnt(0)" ::: "memory");
        __builtin_amdgcn_s_barrier();
        __builtin_amdgcn_sched_barrier(0);
    }

    // colsum reduce: quad butterfly, then cross-wiE via LDS (sP as floats)
    csa += __shfl_xor(csa, 16);
    csa += __shfl_xor(csa, 32);
    float* fb = (float*)sP;
    if (lane < 16) fb[wiE * 128 + wjE * 16 + lane] = csa;
    __syncthreads();
    float csr[2];
    #pragma unroll
    for (int tj = 0; tj < 2; ++tj) {
        const int m = wj * 32 + tj * 16 + m16;
        csr[tj] = 1.0f / (1e-9f + fb[m] + fb[128 + m]);
    }

    // d = h - xr*csr -> sD (fp16, swizzled [128 m][256 c], overlays sXV)
    const half_t* hb = h + (size_t)b * sNC;
    half_t* sD = &sXV[0][0];
    #pragma unroll
    for (int ti = 0; ti < 4; ++ti) {
        const int cg = wi * 64 + ti * 16 + quad * 4;
        const int cc = (cg >> 3) ^ (m16 & 7);      // swizzled 16B chunk
        const int sub = (quad & 1) * 4;
        #pragma unroll
        for (int tj = 0; tj < 2; ++tj) {
            const int mr = wj * 32 + tj * 16 + m16;
            const int mg = j0 + mr;
            const half4 hv = *(const half4*)&hb[(size_t)mg * Cc + cg];
            half4 o;
            #pragma unroll
            for (int r = 0; r < 4; ++r)
                o[r] = (half_t)((float)hv[r] - acc[ti][tj][r] * csr[tj]);
            *(half4*)&sD[(size_t)mr * 256 + cc * 8 + sub] = o;
        }
    }
    __syncthreads();   // sD complete (fb reads also done)

    // T phase: T[co][m] = sum_c tw[co][c] * d[m][c]; tw streamed from L2
    float4v acc2[4][2];
    #pragma unroll
    for (int i = 0; i < 4; ++i)
        #pragma unroll
        for (int j = 0; j < 2; ++j) acc2[i][j] = (float4v)0.f;
    #pragma unroll
    for (int ks = 0; ks < 8; ++ks) {
        half8 af[4], bf[2];
        #pragma unroll
        for (int tm = 0; tm < 4; ++tm)
            af[tm] = *(const half8*)&sD[(size_t)(wiT * 64 + tm * 16 + m16) * 256
                                        + (((ks * 4 + quad) ^ (m16 & 7)) * 8)];
        #pragma unroll
        for (int tc = 0; tc < 2; ++tc)
            bf[tc] = *(const half8*)&tw[(size_t)(wjT * 32 + tc * 16 + m16) * 256
                                        + ks * 32 + quad * 8];
        #pragma unroll
        for (int tm = 0; tm < 4; ++tm)
            #pragma unroll
            for (int tc = 0; tc < 2; ++tc)
                acc2[tm][tc] = __builtin_amdgcn_mfma_f32_16x16x32_f16(
                    af[tm], bf[tc], acc2[tm][tc], 0, 0, 0);
    }

    // epilogue: out = h + relu(bn(T + tb)); hNext fp16
    const long yB = (long)4 * Cc * Nn;
    float* yb = outL + (size_t)b * yB;
    half_t* hn = hNext ? hNext + (size_t)b * sNC : nullptr;
    #pragma unroll
    for (int tc = 0; tc < 2; ++tc) {
        const int co = wjT * 32 + tc * 16 + m16;
        const float tb2 = tb[co];
        const float sc2 = bng[co] * rsqrtf(bnv[co] + 1e-3f);
        const float sh2 = bnb[co] - bnm[co] * sc2;
        #pragma unroll
        for (int tm = 0; tm < 4; ++tm) {
            const int mg = j0 + wiT * 64 + tm * 16 + quad * 4;
            float4v o;
            #pragma unroll
            for (int r = 0; r < 4; ++r) {
                const float t2  = acc2[tm][tc][r] + tb2;
                const float rel = fmaxf(fmaf(t2, sc2, sh2), 0.f);
                const float hv  = (float)hb[(size_t)(mg + r) * Cc + co];
                const float ov  = hv + rel;
                o[r] = ov;
                if (hn) hn[(size_t)(mg + r) * Cc + co] = (half_t)ov;
            }
            *(float4v*)&yb[(size_t)co * Nn + mg] = o;
        }
    }
}

// x [B,C,N] fp32 -> xT [B,N,C] fp16
__global__ __launch_bounds__(256)
void xpose_cast(const float* __restrict__ x, half_t* __restrict__ xT)
{
    __shared__ half_t tile[32][33];
    const int tx = threadIdx.x & 31, ty = threadIdx.x >> 5;
    const int n0 = blockIdx.x * 32, c0 = blockIdx.y * 32, b = blockIdx.z;
    #pragma unroll
    for (int r = 0; r < 4; ++r)
        tile[ty * 4 + r][tx] =
            (half_t)x[((size_t)b * Cc + c0 + ty * 4 + r) * Nn + n0 + tx];
    __syncthreads();
    #pragma unroll
    for (int r = 0; r < 4; ++r)
        xT[((size_t)b * Nn + n0 + ty * 4 + r) * Cc + c0 + tx] = tile[tx][ty * 4 + r];
}

// single kernel casting all 5 weight tensors into one fp16 arena
__global__ __launch_bounds__(256)
void castall(const float* __restrict__ c1, const float* __restrict__ c2,
             const float* __restrict__ qk, const float* __restrict__ vw,
             const float* __restrict__ tw, half_t* __restrict__ dst)
{
    const int i = (blockIdx.x * 256 + threadIdx.x) * 4;   // grid 768 -> 786432 elems
    const float* s; int o;
    if      (i < 65536)  { s = c1; o = 0; }
    else if (i < 131072) { s = c2; o = 65536; }
    else if (i < 196608) { s = qk; o = 131072; }
    else if (i < 458752) { s = vw; o = 196608; }
    else                 { s = tw; o = 458752; }
    const float4v v = *(const float4v*)(s + (i - o));
    half4 out;
    #pragma unroll
    for (int r = 0; r < 4; ++r) out[r] = (half_t)v[r];
    *(half4*)(dst + i) = out;
}

extern "C" void kernel_launch(void* const* d_in, const int* in_sizes, int n_in,
                              void* d_out, int out_size, void* d_ws, size_t ws_size,
                              hipStream_t stream)
{
    const float* x    = (const float*)d_in[0];
    const float* c1w  = (const float*)d_in[1];
    const float* c2w  = (const float*)d_in[2];
    const float* bn1g = (const float*)d_in[3], *bn1b = (const float*)d_in[4];
    const float* bn1m = (const float*)d_in[5], *bn1v = (const float*)d_in[6];
    const float* bn2g = (const float*)d_in[7], *bn2b = (const float*)d_in[8];
    const float* bn2m = (const float*)d_in[9], *bn2v = (const float*)d_in[10];
    const float* qkw  = (const float*)d_in[11];
    const float* vw   = (const float*)d_in[12];
    const float* vb   = (const float*)d_in[13];
    const float* tw   = (const float*)d_in[14];
    const float* tb   = (const float*)d_in[15];
    const float* sag  = (const float*)d_in[16];
    const float* sab  = (const float*)d_in[17];
    const float* sam  = (const float*)d_in[18];
    const float* sav  = (const float*)d_in[19];
    float* out = (float*)d_out;

    // ---- workspace layout ----
    char* ws = (char*)d_ws;
    const size_t HSZ = (size_t)Bn * Nn * Cc * 2;          // 16 MB
    half_t* xT   = (half_t*)(ws);
    half_t* hA   = (half_t*)(ws + HSZ);
    half_t* hBuf = (half_t*)(ws + 2 * HSZ);
    half_t* q_s  = (half_t*)(ws + 3 * HSZ);               // 4 MB
    half_t* xv_s = (half_t*)(ws + 3 * HSZ + (size_t)4194304);       // 16 MB (bf16)
    float*  Pbuf = (float*) (ws + 4 * HSZ + (size_t)4194304);       // 4 MB
    half_t* warena = (half_t*)(ws + 4 * HSZ + (size_t)8388608);     // 1.5 MB
    half_t* wc1  = warena;
    half_t* wc2  = wc1 + 65536;
    half_t* wqk  = wc2 + 65536;
    half_t* wv   = wqk + 65536;
    half_t* wt   = wv  + 262144;

    dim3 blk(256);

    castall<<<768, blk, 0, stream>>>(c1w, c2w, qkw, vw, tw, warena);
    xpose_cast<<<dim3(Nn / 32, Cc / 32, Bn), blk, 0, stream>>>(x, xT);

    // conv1 / conv2 -> h[n][c] fp16. BM=256 covers all C in one i-block so the
    // activation (B operand) is read exactly once.
    mgemm<EPI_H, 256, 128, 4, 2, false><<<dim3(16, 1, Bn), dim3(512), 0, stream>>>(
        wc1, 0, xT, sNC, hA, sNC, Cc,
        nullptr, bn1g, bn1b, bn1m, bn1v, Cc);
    mgemm<EPI_H, 256, 128, 4, 2, false><<<dim3(16, 1, Bn), dim3(512), 0, stream>>>(
        wc2, 0, hA, sNC, hBuf, sNC, Cc,
        nullptr, bn2g, bn2b, bn2m, bn2v, Cc);

    half_t* hcur = hBuf;
    half_t* hnxt = hA;
    for (int L = 0; L < 4; ++L) {
        // q[n][64] fp16
        mgemm<EPI_RAW, 64, 256, 1, 4, false><<<dim3(8, 1, Bn), blk, 0, stream>>>(
            wqk + (long)L * C4 * Cc, 0, hcur, sNC, q_s, sNQ, C4,
            nullptr, nullptr, nullptr, nullptr, nullptr, Cc);
        // softmax stats (no E materialization)
        estats<<<dim3(16, 16, Bn), blk, 0, stream>>>(q_s, Pbuf);
        // xv[c][n] bf16. BN=256 covers all C in one j-block -> hcur read once.
        mgemm<EPI_XV, 128, 256, 2, 4, true><<<dim3(1, 16, Bn), dim3(512), 0, stream>>>(
            hcur, sNC, wv + (long)L * Cc * Cc, 0, xv_s, (long)Cc * Nn, Nn,
            vb + L * Cc, nullptr, nullptr, nullptr, nullptr, Cc);
        // fused: statsreduce + attention-apply + t-GEMM + bn/relu/residual
        // (1-D grid, XCD-aware batch clustering inside the kernel)
        flashxr<<<dim3(256), dim3(1024), 0, stream>>>(
            q_s, xv_s, hcur, Pbuf,
            wt + (long)L * Cc * Cc, tb + L * Cc,
            sag + L * Cc, sab + L * Cc, sam + L * Cc, sav + L * Cc,
            out + (long)L * Cc * Nn, (L < 3) ? hnxt : nullptr);
        half_t* tmp = hcur; hcur = hnxt; hnxt = tmp;
    }
}

// Round 6
// 865.989 us; speedup vs baseline: 1.0344x; 1.0344x over previous
//
#include <hip/hip_runtime.h>
#include <hip/hip_bf16.h>
#include <hip/hip_fp16.h>

// Problem constants: B=16, C=256, N=2048, NUM_SA=4
static constexpr int Bn = 16;
static constexpr int Cc = 256;
static constexpr int Nn = 2048;
static constexpr int C4 = 64;
static constexpr float LOG2E = 1.4426950408889634f;

typedef _Float16 half_t;
typedef __attribute__((ext_vector_type(8))) _Float16 half8;
typedef __attribute__((ext_vector_type(4))) _Float16 half4;
typedef __attribute__((ext_vector_type(8))) short short8;
typedef __attribute__((ext_vector_type(4))) float float4v;

static constexpr long sNC = (long)Nn * Cc;   // 524288
static constexpr long sNQ = (long)Nn * C4;   // 131072

#define DEVI __device__ __forceinline__

DEVI float bf2f(unsigned short u) { return __uint_as_float(((unsigned)u) << 16); }
DEVI unsigned short f2bf(float f) {
    unsigned x = __float_as_uint(f);
    x += 0x7fffu + ((x >> 16) & 1u);   // RNE
    return (unsigned short)(x >> 16);
}

// async global->LDS, 16B per lane. LDS dest = wave-uniform base + lane*16.
DEVI void gload16(const void* g, void* l) {
    __builtin_amdgcn_global_load_lds(
        (const __attribute__((address_space(1))) unsigned int*)g,
        (__attribute__((address_space(3))) unsigned int*)l, 16, 0, 0);
}

enum { EPI_RAW = 0, EPI_H = 1, EPI_XV = 2 };

// Canonical MFMA GEMM: Y[j][i] = epi( sum_k A[i*K+k] * B[j*K+k] )
// NW = WI*WJ waves (NW*64 threads). Wave (wi = w%WI, wj = w/WI) owns a
// 64x64 output tile.
template<int MODE, int BM, int BN, int WI, int WJ, bool BF16OUT>
__global__ __launch_bounds__(WI * WJ * 64)
void mgemm(const half_t* __restrict__ A, long aB,
           const half_t* __restrict__ Bm, long bB,
           void* __restrict__ Yv, long yB, int ldy,
           const float* __restrict__ bias,
           const float* __restrict__ bng, const float* __restrict__ bnb,
           const float* __restrict__ bnm, const float* __restrict__ bnv,
           int K)
{
    constexpr int NW = WI * WJ;
    __shared__ __align__(16) half_t Als[2][BM][32];
    __shared__ __align__(16) half_t Bls[2][BN][32];

    const int tid  = threadIdx.x;
    const int w    = tid >> 6;
    const int lane = tid & 63;
    const int wi   = w % WI;
    const int wj   = w / WI;
    const int quad = lane >> 4, m16 = lane & 15;
    const int lr   = lane >> 2, lc = lane & 3;
    const int b    = blockIdx.z;
    const int j0   = blockIdx.x * BN;
    const int i0   = blockIdx.y * BM;

    const half_t* Ab = A + (size_t)b * aB;
    const half_t* Bb = Bm + (size_t)b * bB;

    float4v acc[4][4];
    #pragma unroll
    for (int i = 0; i < 4; ++i)
        #pragma unroll
        for (int j = 0; j < 4; ++j) acc[i][j] = (float4v)0.f;

    for (int k0 = 0; k0 < K; k0 += 64) {
        #pragma unroll
        for (int s = 0; s < 2; ++s) {
            const int kk = k0 + s * 32 + lc * 8;
            #pragma unroll
            for (int t = 0; t < BM / (16 * NW); ++t) {
                const int row = (t * NW + w) * 16;
                gload16(Ab + (size_t)(i0 + row + lr) * K + kk, &Als[s][row][0]);
            }
            #pragma unroll
            for (int t = 0; t < BN / (16 * NW); ++t) {
                const int row = (t * NW + w) * 16;
                gload16(Bb + (size_t)(j0 + row + lr) * K + kk, &Bls[s][row][0]);
            }
        }
        __syncthreads();
        #pragma unroll
        for (int s = 0; s < 2; ++s) {
            half8 af[4], bf[4];
            #pragma unroll
            for (int t = 0; t < 4; ++t)
                af[t] = *(const half8*)&Als[s][wi * 64 + t * 16 + m16][quad * 8];
            #pragma unroll
            for (int t = 0; t < 4; ++t)
                bf[t] = *(const half8*)&Bls[s][wj * 64 + t * 16 + m16][quad * 8];
            #pragma unroll
            for (int ti = 0; ti < 4; ++ti)
                #pragma unroll
                for (int tj = 0; tj < 4; ++tj)
                    acc[ti][tj] = __builtin_amdgcn_mfma_f32_16x16x32_f16(
                        af[ti], bf[tj], acc[ti][tj], 0, 0, 0);
        }
        __syncthreads();
    }

    #pragma unroll
    for (int ti = 0; ti < 4; ++ti) {
        const int il = i0 + wi * 64 + ti * 16 + quad * 4;
        #pragma unroll
        for (int tj = 0; tj < 4; ++tj) {
            const int jl = j0 + wj * 64 + tj * 16 + m16;
            float4v v = acc[ti][tj];
            if (MODE == EPI_RAW) {
                half4 o;
                #pragma unroll
                for (int r = 0; r < 4; ++r) o[r] = (half_t)v[r];
                *(half4*)((half_t*)Yv + (size_t)b * yB + (size_t)jl * ldy + il) = o;
            } else if (MODE == EPI_H) {
                half4 o;
                #pragma unroll
                for (int r = 0; r < 4; ++r) {
                    const float sc = bng[il + r] * rsqrtf(bnv[il + r] + 1e-3f);
                    const float sh = bnb[il + r] - bnm[il + r] * sc;
                    o[r] = (half_t)fmaxf(fmaf(v[r], sc, sh), 0.f);
                }
                *(half4*)((half_t*)Yv + (size_t)b * yB + (size_t)jl * ldy + il) = o;
            } else {   // EPI_XV
                const float bj = bias[jl];
                if (BF16OUT) {
                    ushort4 o;
                    o.x = f2bf(v[0] + bj); o.y = f2bf(v[1] + bj);
                    o.z = f2bf(v[2] + bj); o.w = f2bf(v[3] + bj);
                    *(ushort4*)((unsigned short*)Yv + (size_t)b * yB + (size_t)jl * ldy + il) = o;
                } else {
                    half4 o;
                    #pragma unroll
                    for (int r = 0; r < 4; ++r) o[r] = (half_t)(v[r] + bj);
                    *(half4*)((half_t*)Yv + (size_t)b * yB + (size_t)jl * ldy + il) = o;
                }
            }
        }
    }
}

// Pass 1: E = q q^T tile (i=n rows, j=m cols, K=64), NO E store.
// Per-block per-column (max, sumexp) partials -> Pbuf[b][m][16 iblk][2].
__global__ __launch_bounds__(256)
void estats(const half_t* __restrict__ q, float* __restrict__ Pbuf)
{
    __shared__ __align__(16) half_t sA[128 * 64];
    __shared__ __align__(16) half_t sB[128 * 64];
    __shared__ float red[2][2][4][16][2];
    const int tid = threadIdx.x, w = tid >> 6, lane = tid & 63;
    const int wi = w & 1, wj = w >> 1, quad = lane >> 4, m16 = lane & 15;
    const int b = blockIdx.z, j0 = blockIdx.x * 128, i0 = blockIdx.y * 128;
    const half_t* qb = q + (size_t)b * sNQ;

    #pragma unroll
    for (int t = 0; t < 4; ++t) {
        const int g = w * 256 + t * 64 + lane;
        const int r = g >> 3, c = g & 7;
        const int cs = c ^ (r & 7);
        gload16(qb + (size_t)(i0 + r) * 64 + cs * 8, sA + (w * 256 + t * 64) * 8);
        gload16(qb + (size_t)(j0 + r) * 64 + cs * 8, sB + (w * 256 + t * 64) * 8);
    }
    __syncthreads();

    half8 an[4][2], bm[4][2];
    #pragma unroll
    for (int t = 0; t < 4; ++t)
        #pragma unroll
        for (int ks = 0; ks < 2; ++ks) {
            const int pc = ((ks * 4 + quad) ^ (m16 & 7)) * 8;
            an[t][ks] = *(const half8*)&sA[(wi * 64 + t * 16 + m16) * 64 + pc];
            bm[t][ks] = *(const half8*)&sB[(wj * 64 + t * 16 + m16) * 64 + pc];
        }

    #pragma unroll
    for (int tj = 0; tj < 4; ++tj) {
        float4v e[4];
        #pragma unroll
        for (int ti = 0; ti < 4; ++ti) {
            e[ti] = (float4v)0.f;
            e[ti] = __builtin_amdgcn_mfma_f32_16x16x32_f16(an[ti][0], bm[tj][0], e[ti], 0, 0, 0);
            e[ti] = __builtin_amdgcn_mfma_f32_16x16x32_f16(an[ti][1], bm[tj][1], e[ti], 0, 0, 0);
        }
        float lmax = -1e30f;
        #pragma unroll
        for (int ti = 0; ti < 4; ++ti)
            #pragma unroll
            for (int r = 0; r < 4; ++r) lmax = fmaxf(lmax, e[ti][r]);
        lmax = fmaxf(lmax, __shfl_xor(lmax, 16));
        lmax = fmaxf(lmax, __shfl_xor(lmax, 32));
        float ls = 0.f;
        #pragma unroll
        for (int ti = 0; ti < 4; ++ti)
            #pragma unroll
            for (int r = 0; r < 4; ++r) ls += __expf(e[ti][r] - lmax);
        ls += __shfl_xor(ls, 16);
        ls += __shfl_xor(ls, 32);
        if (quad == 0) { red[wi][wj][tj][m16][0] = lmax; red[wi][wj][tj][m16][1] = ls; }
    }
    __syncthreads();
    if (tid < 128) {
        const int wj2 = tid >> 6, tj2 = (tid >> 4) & 3, mm = tid & 15;
        const float m0 = red[0][wj2][tj2][mm][0], s0 = red[0][wj2][tj2][mm][1];
        const float m1 = red[1][wj2][tj2][mm][0], s1 = red[1][wj2][tj2][mm][1];
        const float M = fmaxf(m0, m1);
        const float S = s0 * __expf(m0 - M) + s1 * __expf(m1 - M);
        const int m = j0 + wj2 * 64 + tj2 * 16 + mm;
        *(float2*)(Pbuf + (((size_t)b * Nn + m) * 16 + blockIdx.y) * 2) = make_float2(M, S);
    }
}

// Pass 2: fused attention-apply + t-GEMM + bn/relu/residual epilogue.
// 512 threads (8 waves), 1 block per (b, m-64-tile) -> 512 blocks,
// 48 KB LDS -> 2-3 co-resident blocks/CU: independent barrier domains
// overlap each other's stalls (m114 mechanism; the round-4 single-domain
// 16-wave version serialized on every dependency and regressed).
// XCD mapping: W = (bid%8)*64 + bid/8 -> XCD r owns batches {2r, 2r+1}.
// Per chunk (32 x 64 n): stage sXV (gload_lds) | direct-L2 q A-frags ->
//   E MFMA + exp + pack -> sP -> barrier (drains stage, partially hidden,
//   sibling block overlaps the rest) -> XR MFMAs -> barrier.
__global__ __launch_bounds__(512)
void flashxr(const half_t* __restrict__ q, const half_t* __restrict__ xv,
             const half_t* __restrict__ h, const float* __restrict__ Pbuf,
             const half_t* __restrict__ tw, const float* __restrict__ tb,
             const float* __restrict__ bng, const float* __restrict__ bnb,
             const float* __restrict__ bnm, const float* __restrict__ bnv,
             float* __restrict__ outL, half_t* __restrict__ hNext)
{
    __shared__ __align__(16) half_t sXV[256 * 64];   // 32 KB; reused as sD[64][256]
    __shared__ __align__(16) half_t sP[64 * 64];     // 8 KB: P tile / cs buf
    __shared__ float sOff[Nn];                       // 8 KB

    const int tid = threadIdx.x, w = tid >> 6, lane = tid & 63;
    const int quad = lane >> 4, m16 = lane & 15;
    const int wiE = w & 1, wjE = w >> 1;        // E: n-32-half, m-16-tile (4)
    const int wi = w & 3, wj = w >> 2;          // XR: c-64-tile (4), m-32-tile (2)
    const int wjT = w;                          // T: co-32-tile (8)
    // XCD-aware (b, j0) assignment from 1-D block id (XCD = bid % 8)
    const int f = blockIdx.x;
    const int W = (f & 7) * 64 + (f >> 3);      // bijective over [0,512)
    const int b = W >> 5, j0 = (W & 31) * 64;
    const half_t* qb  = q + (size_t)b * sNQ;
    const half_t* xvb = xv + (size_t)b * sNC;   // [256][2048] bf16 bits

    // ---- prologue: bq fragments (one-time, L2) + statsreduce -> sOff ----
    half8 bq[2];
    #pragma unroll
    for (int s = 0; s < 2; ++s)
        bq[s] = *(const half8*)(qb + (size_t)(j0 + wjE * 16 + m16) * 64 + (s * 4 + quad) * 8);

    {   // off[n] = M*log2e + log2(S) from 16 per-block partials
        const float* pB = Pbuf + (size_t)b * Nn * 32;
        for (int i = tid; i < Nn; i += 512) {
            const float4v* p4 = (const float4v*)(pB + (size_t)i * 32);
            float4v v[8];
            #pragma unroll
            for (int t = 0; t < 8; ++t) v[t] = p4[t];
            float M = -1e30f;
            #pragma unroll
            for (int t = 0; t < 8; ++t) { M = fmaxf(M, v[t][0]); M = fmaxf(M, v[t][2]); }
            float S = 0.f;
            #pragma unroll
            for (int t = 0; t < 8; ++t) {
                S += v[t][1] * __expf(v[t][0] - M);
                S += v[t][3] * __expf(v[t][2] - M);
            }
            sOff[i] = fmaf(M, LOG2E, __log2f(S));
        }
    }
    __syncthreads();

    float4v acc[4][2];
    #pragma unroll
    for (int i = 0; i < 4; ++i)
        #pragma unroll
        for (int j = 0; j < 2; ++j) acc[i][j] = (float4v)0.f;
    float csa = 0.f;

    const int mrow = wjE * 16 + m16;

    for (int nc = 0; nc < 32; ++nc) {
        // stage sXV chunk: 256 c rows x 64 n (swizzled), 4 gload16/thread
        #pragma unroll
        for (int t = 0; t < 4; ++t) {
            const int g = t * 512 + tid;
            const int r = g >> 3, c = g & 7;
            gload16(xvb + (size_t)r * Nn + nc * 64 + ((c ^ (r & 7)) * 8),
                    sXV + (size_t)g * 8);
        }

        // E A-fragments direct from L2 (q XCD-resident); E = 2 n-16 tiles/wave
        half8 an[2][2];
        #pragma unroll
        for (int ti = 0; ti < 2; ++ti)
            #pragma unroll
            for (int s = 0; s < 2; ++s)
                an[ti][s] = *(const half8*)(qb
                    + (size_t)(nc * 64 + wiE * 32 + ti * 16 + m16) * 64
                    + (s * 4 + quad) * 8);

        #pragma unroll
        for (int ti = 0; ti < 2; ++ti) {
            float4v e = (float4v)0.f;
            e = __builtin_amdgcn_mfma_f32_16x16x32_f16(an[ti][0], bq[0], e, 0, 0, 0);
            e = __builtin_amdgcn_mfma_f32_16x16x32_f16(an[ti][1], bq[1], e, 0, 0, 0);
            const float4v o4 = *(const float4v*)&sOff[nc * 64 + wiE * 32 + ti * 16 + quad * 4];
            float c0 = 0.f; ushort4 pk;
            #pragma unroll
            for (int r = 0; r < 4; ++r) {
                const float p = __builtin_amdgcn_exp2f(fmaf(e[r], LOG2E, -o4[r]));
                c0 += p; (&pk.x)[r] = f2bf(p);
            }
            csa += c0;
            const int pc = (wiE * 4 + ti * 2 + (quad >> 1)) ^ (m16 & 7);
            *(ushort4*)&((unsigned short*)sP)[(size_t)mrow * 64 + pc * 8 + (quad & 1) * 4] = pk;
        }
        __syncthreads();   // drains sXV stage (partially hidden); publishes sP

        // XR phase: acc[c][m] += xv[c][k=n] * P[m][k=n], K = 64
        #pragma unroll
        for (int ks = 0; ks < 2; ++ks) {
            short8 xa[4], pb[2];
            #pragma unroll
            for (int ti = 0; ti < 4; ++ti)
                xa[ti] = *(const short8*)&sXV[(size_t)(wi * 64 + ti * 16 + m16) * 64
                                              + (((ks * 4 + quad) ^ (m16 & 7)) * 8)];
            #pragma unroll
            for (int tj = 0; tj < 2; ++tj)
                pb[tj] = *(const short8*)&sP[(size_t)(wj * 32 + tj * 16 + m16) * 64
                                             + (((ks * 4 + quad) ^ (m16 & 7)) * 8)];
            __builtin_amdgcn_s_setprio(1);
            #pragma unroll
            for (int ti = 0; ti < 4; ++ti)
                #pragma unroll
                for (int tj = 0; tj < 2; ++tj)
                    acc[ti][tj] = __builtin_amdgcn_mfma_f32_16x16x32_bf16(
                        xa[ti], pb[tj], acc[ti][tj], 0, 0, 0);
            __builtin_amdgcn_s_setprio(0);
        }
        __syncthreads();   // XR reads done before next chunk overwrites
    }

    // colsum reduce: quad butterfly, then cross-wiE via LDS (sP as floats)
    csa += __shfl_xor(csa, 16);
    csa += __shfl_xor(csa, 32);
    float* fb = (float*)sP;
    if (lane < 16) fb[wiE * 64 + wjE * 16 + lane] = csa;
    __syncthreads();
    float csr[2];
    #pragma unroll
    for (int tj = 0; tj < 2; ++tj) {
        const int m = wj * 32 + tj * 16 + m16;
        csr[tj] = 1.0f / (1e-9f + fb[m] + fb[64 + m]);
    }

    // d = h - xr*csr -> sD (fp16, swizzled [64 m][256 c], overlays sXV)
    const half_t* hb = h + (size_t)b * sNC;
    half_t* sD = sXV;
    #pragma unroll
    for (int ti = 0; ti < 4; ++ti) {
        const int cg = wi * 64 + ti * 16 + quad * 4;
        const int cc = (cg >> 3) ^ (m16 & 7);      // swizzled 16B chunk
        const int sub = (quad & 1) * 4;
        #pragma unroll
        for (int tj = 0; tj < 2; ++tj) {
            const int mr = wj * 32 + tj * 16 + m16;
            const int mg = j0 + mr;
            const half4 hv = *(const half4*)&hb[(size_t)mg * Cc + cg];
            half4 o;
            #pragma unroll
            for (int r = 0; r < 4; ++r)
                o[r] = (half_t)((float)hv[r] - acc[ti][tj][r] * csr[tj]);
            *(half4*)&sD[(size_t)mr * 256 + cc * 8 + sub] = o;
        }
    }
    __syncthreads();   // sD complete (fb reads also done)

    // T phase: T[co][m] = sum_c tw[co][c] * d[m][c]; tw streamed from L2
    float4v acc2[4][2];
    #pragma unroll
    for (int i = 0; i < 4; ++i)
        #pragma unroll
        for (int j = 0; j < 2; ++j) acc2[i][j] = (float4v)0.f;
    #pragma unroll
    for (int ks = 0; ks < 8; ++ks) {
        half8 af[4], bf[2];
        #pragma unroll
        for (int tm = 0; tm < 4; ++tm)
            af[tm] = *(const half8*)&sD[(size_t)(tm * 16 + m16) * 256
                                        + (((ks * 4 + quad) ^ (m16 & 7)) * 8)];
        #pragma unroll
        for (int tc = 0; tc < 2; ++tc)
            bf[tc] = *(const half8*)&tw[(size_t)(wjT * 32 + tc * 16 + m16) * 256
                                        + ks * 32 + quad * 8];
        #pragma unroll
        for (int tm = 0; tm < 4; ++tm)
            #pragma unroll
            for (int tc = 0; tc < 2; ++tc)
                acc2[tm][tc] = __builtin_amdgcn_mfma_f32_16x16x32_f16(
                    af[tm], bf[tc], acc2[tm][tc], 0, 0, 0);
    }

    // epilogue: out = h + relu(bn(T + tb)); hNext fp16
    const long yB = (long)4 * Cc * Nn;
    float* yb = outL + (size_t)b * yB;
    half_t* hn = hNext ? hNext + (size_t)b * sNC : nullptr;
    #pragma unroll
    for (int tc = 0; tc < 2; ++tc) {
        const int co = wjT * 32 + tc * 16 + m16;
        const float tb2 = tb[co];
        const float sc2 = bng[co] * rsqrtf(bnv[co] + 1e-3f);
        const float sh2 = bnb[co] - bnm[co] * sc2;
        #pragma unroll
        for (int tm = 0; tm < 4; ++tm) {
            const int mg = j0 + tm * 16 + quad * 4;
            float4v o;
            #pragma unroll
            for (int r = 0; r < 4; ++r) {
                const float t2  = acc2[tm][tc][r] + tb2;
                const float rel = fmaxf(fmaf(t2, sc2, sh2), 0.f);
                const float hv  = (float)hb[(size_t)(mg + r) * Cc + co];
                const float ov  = hv + rel;
                o[r] = ov;
                if (hn) hn[(size_t)(mg + r) * Cc + co] = (half_t)ov;
            }
            *(float4v*)&yb[(size_t)co * Nn + mg] = o;
        }
    }
}

// x [B,C,N] fp32 -> xT [B,N,C] fp16
__global__ __launch_bounds__(256)
void xpose_cast(const float* __restrict__ x, half_t* __restrict__ xT)
{
    __shared__ half_t tile[32][33];
    const int tx = threadIdx.x & 31, ty = threadIdx.x >> 5;
    const int n0 = blockIdx.x * 32, c0 = blockIdx.y * 32, b = blockIdx.z;
    #pragma unroll
    for (int r = 0; r < 4; ++r)
        tile[ty * 4 + r][tx] =
            (half_t)x[((size_t)b * Cc + c0 + ty * 4 + r) * Nn + n0 + tx];
    __syncthreads();
    #pragma unroll
    for (int r = 0; r < 4; ++r)
        xT[((size_t)b * Nn + n0 + ty * 4 + r) * Cc + c0 + tx] = tile[tx][ty * 4 + r];
}

// single kernel casting all 5 weight tensors into one fp16 arena
__global__ __launch_bounds__(256)
void castall(const float* __restrict__ c1, const float* __restrict__ c2,
             const float* __restrict__ qk, const float* __restrict__ vw,
             const float* __restrict__ tw, half_t* __restrict__ dst)
{
    const int i = (blockIdx.x * 256 + threadIdx.x) * 4;   // grid 768 -> 786432 elems
    const float* s; int o;
    if      (i < 65536)  { s = c1; o = 0; }
    else if (i < 131072) { s = c2; o = 65536; }
    else if (i < 196608) { s = qk; o = 131072; }
    else if (i < 458752) { s = vw; o = 196608; }
    else                 { s = tw; o = 458752; }
    const float4v v = *(const float4v*)(s + (i - o));
    half4 out;
    #pragma unroll
    for (int r = 0; r < 4; ++r) out[r] = (half_t)v[r];
    *(half4*)(dst + i) = out;
}

extern "C" void kernel_launch(void* const* d_in, const int* in_sizes, int n_in,
                              void* d_out, int out_size, void* d_ws, size_t ws_size,
                              hipStream_t stream)
{
    const float* x    = (const float*)d_in[0];
    const float* c1w  = (const float*)d_in[1];
    const float* c2w  = (const float*)d_in[2];
    const float* bn1g = (const float*)d_in[3], *bn1b = (const float*)d_in[4];
    const float* bn1m = (const float*)d_in[5], *bn1v = (const float*)d_in[6];
    const float* bn2g = (const float*)d_in[7], *bn2b = (const float*)d_in[8];
    const float* bn2m = (const float*)d_in[9], *bn2v = (const float*)d_in[10];
    const float* qkw  = (const float*)d_in[11];
    const float* vw   = (const float*)d_in[12];
    const float* vb   = (const float*)d_in[13];
    const float* tw   = (const float*)d_in[14];
    const float* tb   = (const float*)d_in[15];
    const float* sag  = (const float*)d_in[16];
    const float* sab  = (const float*)d_in[17];
    const float* sam  = (const float*)d_in[18];
    const float* sav  = (const float*)d_in[19];
    float* out = (float*)d_out;

    // ---- workspace layout ----
    char* ws = (char*)d_ws;
    const size_t HSZ = (size_t)Bn * Nn * Cc * 2;          // 16 MB
    half_t* xT   = (half_t*)(ws);
    half_t* hA   = (half_t*)(ws + HSZ);
    half_t* hBuf = (half_t*)(ws + 2 * HSZ);
    half_t* q_s  = (half_t*)(ws + 3 * HSZ);               // 4 MB
    half_t* xv_s = (half_t*)(ws + 3 * HSZ + (size_t)4194304);       // 16 MB (bf16)
    float*  Pbuf = (float*) (ws + 4 * HSZ + (size_t)4194304);       // 4 MB
    half_t* warena = (half_t*)(ws + 4 * HSZ + (size_t)8388608);     // 1.5 MB
    half_t* wc1  = warena;
    half_t* wc2  = wc1 + 65536;
    half_t* wqk  = wc2 + 65536;
    half_t* wv   = wqk + 65536;
    half_t* wt   = wv  + 262144;

    dim3 blk(256);

    castall<<<768, blk, 0, stream>>>(c1w, c2w, qkw, vw, tw, warena);
    xpose_cast<<<dim3(Nn / 32, Cc / 32, Bn), blk, 0, stream>>>(x, xT);

    // conv1 / conv2 -> h[n][c] fp16. BM=256 covers all C in one i-block so the
    // activation (B operand) is read exactly once.
    mgemm<EPI_H, 256, 128, 4, 2, false><<<dim3(16, 1, Bn), dim3(512), 0, stream>>>(
        wc1, 0, xT, sNC, hA, sNC, Cc,
        nullptr, bn1g, bn1b, bn1m, bn1v, Cc);
    mgemm<EPI_H, 256, 128, 4, 2, false><<<dim3(16, 1, Bn), dim3(512), 0, stream>>>(
        wc2, 0, hA, sNC, hBuf, sNC, Cc,
        nullptr, bn2g, bn2b, bn2m, bn2v, Cc);

    half_t* hcur = hBuf;
    half_t* hnxt = hA;
    for (int L = 0; L < 4; ++L) {
        // q[n][64] fp16
        mgemm<EPI_RAW, 64, 256, 1, 4, false><<<dim3(8, 1, Bn), blk, 0, stream>>>(
            wqk + (long)L * C4 * Cc, 0, hcur, sNC, q_s, sNQ, C4,
            nullptr, nullptr, nullptr, nullptr, nullptr, Cc);
        // softmax stats (no E materialization)
        estats<<<dim3(16, 16, Bn), blk, 0, stream>>>(q_s, Pbuf);
        // xv[c][n] bf16. BN=256 covers all C in one j-block -> hcur read once.
        mgemm<EPI_XV, 128, 256, 2, 4, true><<<dim3(1, 16, Bn), dim3(512), 0, stream>>>(
            hcur, sNC, wv + (long)L * Cc * Cc, 0, xv_s, (long)Cc * Nn, Nn,
            vb + L * Cc, nullptr, nullptr, nullptr, nullptr, Cc);
        // fused: statsreduce + attention-apply + t-GEMM + bn/relu/residual
        // (512 blocks x 512 threads; 2+ independent barrier domains per CU)
        flashxr<<<dim3(512), dim3(512), 0, stream>>>(
            q_s, xv_s, hcur, Pbuf,
            wt + (long)L * Cc * Cc, tb + L * Cc,
            sag + L * Cc, sab + L * Cc, sam + L * Cc, sav + L * Cc,
            out + (long)L * Cc * Nn, (L < 3) ? hnxt : nullptr);
        half_t* tmp = hcur; hcur = hnxt; hnxt = tmp;
    }
}

// Round 7
// 695.911 us; speedup vs baseline: 1.2872x; 1.2444x over previous
//
#include <hip/hip_runtime.h>
#include <hip/hip_bf16.h>
#include <hip/hip_fp16.h>

// Problem constants: B=16, C=256, N=2048, NUM_SA=4
static constexpr int Bn = 16;
static constexpr int Cc = 256;
static constexpr int Nn = 2048;
static constexpr int C4 = 64;
static constexpr float LOG2E = 1.4426950408889634f;

typedef _Float16 half_t;
typedef __attribute__((ext_vector_type(8))) _Float16 half8;
typedef __attribute__((ext_vector_type(4))) _Float16 half4;
typedef __attribute__((ext_vector_type(8))) short short8;
typedef __attribute__((ext_vector_type(4))) float float4v;

static constexpr long sNC = (long)Nn * Cc;   // 524288
static constexpr long sNQ = (long)Nn * C4;   // 131072

#define DEVI __device__ __forceinline__

DEVI float bf2f(unsigned short u) { return __uint_as_float(((unsigned)u) << 16); }
DEVI unsigned short f2bf(float f) {
    unsigned x = __float_as_uint(f);
    x += 0x7fffu + ((x >> 16) & 1u);   // RNE
    return (unsigned short)(x >> 16);
}

// async global->LDS, 16B per lane. LDS dest = wave-uniform base + lane*16.
DEVI void gload16(const void* g, void* l) {
    __builtin_amdgcn_global_load_lds(
        (const __attribute__((address_space(1))) unsigned int*)g,
        (__attribute__((address_space(3))) unsigned int*)l, 16, 0, 0);
}

enum { EPI_RAW = 0, EPI_H = 1, EPI_XV = 2 };

// Canonical MFMA GEMM: Y[j][i] = epi( sum_k A[i*K+k] * B[j*K+k] )
template<int MODE, int BM, int BN, int WI, int WJ, bool BF16OUT>
__global__ __launch_bounds__(WI * WJ * 64)
void mgemm(const half_t* __restrict__ A, long aB,
           const half_t* __restrict__ Bm, long bB,
           void* __restrict__ Yv, long yB, int ldy,
           const float* __restrict__ bias,
           const float* __restrict__ bng, const float* __restrict__ bnb,
           const float* __restrict__ bnm, const float* __restrict__ bnv,
           int K)
{
    constexpr int NW = WI * WJ;
    __shared__ __align__(16) half_t Als[2][BM][32];
    __shared__ __align__(16) half_t Bls[2][BN][32];

    const int tid  = threadIdx.x;
    const int w    = tid >> 6;
    const int lane = tid & 63;
    const int wi   = w % WI;
    const int wj   = w / WI;
    const int quad = lane >> 4, m16 = lane & 15;
    const int lr   = lane >> 2, lc = lane & 3;
    const int b    = blockIdx.z;
    const int j0   = blockIdx.x * BN;
    const int i0   = blockIdx.y * BM;

    const half_t* Ab = A + (size_t)b * aB;
    const half_t* Bb = Bm + (size_t)b * bB;

    float4v acc[4][4];
    #pragma unroll
    for (int i = 0; i < 4; ++i)
        #pragma unroll
        for (int j = 0; j < 4; ++j) acc[i][j] = (float4v)0.f;

    for (int k0 = 0; k0 < K; k0 += 64) {
        #pragma unroll
        for (int s = 0; s < 2; ++s) {
            const int kk = k0 + s * 32 + lc * 8;
            #pragma unroll
            for (int t = 0; t < BM / (16 * NW); ++t) {
                const int row = (t * NW + w) * 16;
                gload16(Ab + (size_t)(i0 + row + lr) * K + kk, &Als[s][row][0]);
            }
            #pragma unroll
            for (int t = 0; t < BN / (16 * NW); ++t) {
                const int row = (t * NW + w) * 16;
                gload16(Bb + (size_t)(j0 + row + lr) * K + kk, &Bls[s][row][0]);
            }
        }
        __syncthreads();
        #pragma unroll
        for (int s = 0; s < 2; ++s) {
            half8 af[4], bf[4];
            #pragma unroll
            for (int t = 0; t < 4; ++t)
                af[t] = *(const half8*)&Als[s][wi * 64 + t * 16 + m16][quad * 8];
            #pragma unroll
            for (int t = 0; t < 4; ++t)
                bf[t] = *(const half8*)&Bls[s][wj * 64 + t * 16 + m16][quad * 8];
            #pragma unroll
            for (int ti = 0; ti < 4; ++ti)
                #pragma unroll
                for (int tj = 0; tj < 4; ++tj)
                    acc[ti][tj] = __builtin_amdgcn_mfma_f32_16x16x32_f16(
                        af[ti], bf[tj], acc[ti][tj], 0, 0, 0);
        }
        __syncthreads();
    }

    #pragma unroll
    for (int ti = 0; ti < 4; ++ti) {
        const int il = i0 + wi * 64 + ti * 16 + quad * 4;
        #pragma unroll
        for (int tj = 0; tj < 4; ++tj) {
            const int jl = j0 + wj * 64 + tj * 16 + m16;
            float4v v = acc[ti][tj];
            if (MODE == EPI_RAW) {
                half4 o;
                #pragma unroll
                for (int r = 0; r < 4; ++r) o[r] = (half_t)v[r];
                *(half4*)((half_t*)Yv + (size_t)b * yB + (size_t)jl * ldy + il) = o;
            } else if (MODE == EPI_H) {
                half4 o;
                #pragma unroll
                for (int r = 0; r < 4; ++r) {
                    const float sc = bng[il + r] * rsqrtf(bnv[il + r] + 1e-3f);
                    const float sh = bnb[il + r] - bnm[il + r] * sc;
                    o[r] = (half_t)fmaxf(fmaf(v[r], sc, sh), 0.f);
                }
                *(half4*)((half_t*)Yv + (size_t)b * yB + (size_t)jl * ldy + il) = o;
            } else {   // EPI_XV
                const float bj = bias[jl];
                if (BF16OUT) {
                    ushort4 o;
                    o.x = f2bf(v[0] + bj); o.y = f2bf(v[1] + bj);
                    o.z = f2bf(v[2] + bj); o.w = f2bf(v[3] + bj);
                    *(ushort4*)((unsigned short*)Yv + (size_t)b * yB + (size_t)jl * ldy + il) = o;
                } else {
                    half4 o;
                    #pragma unroll
                    for (int r = 0; r < 4; ++r) o[r] = (half_t)(v[r] + bj);
                    *(half4*)((half_t*)Yv + (size_t)b * yB + (size_t)jl * ldy + il) = o;
                }
            }
        }
    }
}

// Pass 1: E = q q^T tile stats (no E store) -> Pbuf[b][m][16 iblk][2].
__global__ __launch_bounds__(256)
void estats(const half_t* __restrict__ q, float* __restrict__ Pbuf)
{
    __shared__ __align__(16) half_t sA[128 * 64];
    __shared__ __align__(16) half_t sB[128 * 64];
    __shared__ float red[2][2][4][16][2];
    const int tid = threadIdx.x, w = tid >> 6, lane = tid & 63;
    const int wi = w & 1, wj = w >> 1, quad = lane >> 4, m16 = lane & 15;
    const int b = blockIdx.z, j0 = blockIdx.x * 128, i0 = blockIdx.y * 128;
    const half_t* qb = q + (size_t)b * sNQ;

    #pragma unroll
    for (int t = 0; t < 4; ++t) {
        const int g = w * 256 + t * 64 + lane;
        const int r = g >> 3, c = g & 7;
        const int cs = c ^ (r & 7);
        gload16(qb + (size_t)(i0 + r) * 64 + cs * 8, sA + (w * 256 + t * 64) * 8);
        gload16(qb + (size_t)(j0 + r) * 64 + cs * 8, sB + (w * 256 + t * 64) * 8);
    }
    __syncthreads();

    half8 an[4][2], bm[4][2];
    #pragma unroll
    for (int t = 0; t < 4; ++t)
        #pragma unroll
        for (int ks = 0; ks < 2; ++ks) {
            const int pc = ((ks * 4 + quad) ^ (m16 & 7)) * 8;
            an[t][ks] = *(const half8*)&sA[(wi * 64 + t * 16 + m16) * 64 + pc];
            bm[t][ks] = *(const half8*)&sB[(wj * 64 + t * 16 + m16) * 64 + pc];
        }

    #pragma unroll
    for (int tj = 0; tj < 4; ++tj) {
        float4v e[4];
        #pragma unroll
        for (int ti = 0; ti < 4; ++ti) {
            e[ti] = (float4v)0.f;
            e[ti] = __builtin_amdgcn_mfma_f32_16x16x32_f16(an[ti][0], bm[tj][0], e[ti], 0, 0, 0);
            e[ti] = __builtin_amdgcn_mfma_f32_16x16x32_f16(an[ti][1], bm[tj][1], e[ti], 0, 0, 0);
        }
        float lmax = -1e30f;
        #pragma unroll
        for (int ti = 0; ti < 4; ++ti)
            #pragma unroll
            for (int r = 0; r < 4; ++r) lmax = fmaxf(lmax, e[ti][r]);
        lmax = fmaxf(lmax, __shfl_xor(lmax, 16));
        lmax = fmaxf(lmax, __shfl_xor(lmax, 32));
        float ls = 0.f;
        #pragma unroll
        for (int ti = 0; ti < 4; ++ti)
            #pragma unroll
            for (int r = 0; r < 4; ++r) ls += __expf(e[ti][r] - lmax);
        ls += __shfl_xor(ls, 16);
        ls += __shfl_xor(ls, 32);
        if (quad == 0) { red[wi][wj][tj][m16][0] = lmax; red[wi][wj][tj][m16][1] = ls; }
    }
    __syncthreads();
    if (tid < 128) {
        const int wj2 = tid >> 6, tj2 = (tid >> 4) & 3, mm = tid & 15;
        const float m0 = red[0][wj2][tj2][mm][0], s0 = red[0][wj2][tj2][mm][1];
        const float m1 = red[1][wj2][tj2][mm][0], s1 = red[1][wj2][tj2][mm][1];
        const float M = fmaxf(m0, m1);
        const float S = s0 * __expf(m0 - M) + s1 * __expf(m1 - M);
        const int m = j0 + wj2 * 64 + tj2 * 16 + mm;
        *(float2*)(Pbuf + (((size_t)b * Nn + m) * 16 + blockIdx.y) * 2) = make_float2(M, S);
    }
}

// Pass 2: fused attention-apply + t-GEMM + epilogue. 1024 threads (16 waves),
// 1 block per (b, m-128-tile), XCD-aware mapping (round-3 compute bodies).
// Counted-wait pipeline (T3+T4): 32 chunks of 64 n. Per chunk:
//   [issue next-chunk gload_lds stages] -> vmcnt(K counted, NEVER 0 mid-loop)
//   -> s_barrier -> E (all operands from LDS) -> lgkmcnt(0)+s_barrier -> XR.
// sXV triple-buffered (stage target never read this or last chunk);
// sQA double-buffered at 128-row granularity (staged every 2 chunks).
// LDS: 96 (sXV) + 32 (sQA) + 16 (sP) + 8 (sOff) = 152 KB -> 1 block/CU.
__global__ __launch_bounds__(1024)
void flashxr(const half_t* __restrict__ q, const half_t* __restrict__ xv,
             const half_t* __restrict__ h, const float* __restrict__ Pbuf,
             const half_t* __restrict__ tw, const float* __restrict__ tb,
             const float* __restrict__ bng, const float* __restrict__ bnb,
             const float* __restrict__ bnm, const float* __restrict__ bnv,
             float* __restrict__ outL, half_t* __restrict__ hNext)
{
    constexpr int XSZ = 256 * 64;                      // halfs per sXV buffer
    __shared__ __align__(16) half_t sXV[3][XSZ];       // 96 KB triple-buffered
    __shared__ __align__(16) half_t sQA[2][128 * 64];  // 32 KB, 2-chunk granule
    __shared__ __align__(16) half_t sP[128 * 64];      // 16 KB P tile / cs buf
    __shared__ float sOff[Nn];                         // 8 KB

    const int tid = threadIdx.x, w = tid >> 6, lane = tid & 63;
    const int quad = lane >> 4, m16 = lane & 15;
    const int wiE = w & 1, wjE = w >> 1;        // E: n-32-half, m-16-tile (8)
    const int wi = w & 3, wj = w >> 2;          // XR: c-64-tile (4), m-32-tile (4)
    const int wiT = w & 1, wjT = w >> 1;        // T: m-half, co-32-tile (8)
    const int f = blockIdx.x;
    const int W = (f & 7) * 32 + (f >> 3);      // XCD-contiguous work id
    const int b = W >> 4, j0 = (W & 15) * 128;
    const half_t* qb  = q + (size_t)b * sNQ;
    const half_t* xvb = xv + (size_t)b * sNC;   // [256][2048] bf16 bits

    const int sr = tid >> 3, sc = tid & 7;      // 128-row staging coords (sQA)
    const int qsw = (sc ^ (sr & 7)) * 8;

    // ---- prologue: stage chunk0 sXV + sQA[0]; bq regs; statsreduce ----
    #pragma unroll
    for (int t = 0; t < 2; ++t) {
        const int g = t * 1024 + tid;
        const int r = g >> 3, c = g & 7;
        gload16(xvb + (size_t)r * Nn + ((c ^ (r & 7)) * 8), &sXV[0][(size_t)g * 8]);
    }
    gload16(qb + (size_t)sr * 64 + qsw, &sQA[0][(size_t)tid * 8]);

    half8 bq[2];
    #pragma unroll
    for (int s = 0; s < 2; ++s)
        bq[s] = *(const half8*)(qb + (size_t)(j0 + wjE * 16 + m16) * 64 + (s * 4 + quad) * 8);

    {   // off[n] = M*log2e + log2(S) from 16 per-block partials
        const float* pB = Pbuf + (size_t)b * Nn * 32;
        for (int i = tid; i < Nn; i += 1024) {
            const float4v* p4 = (const float4v*)(pB + (size_t)i * 32);
            float4v v[8];
            #pragma unroll
            for (int t = 0; t < 8; ++t) v[t] = p4[t];
            float M = -1e30f;
            #pragma unroll
            for (int t = 0; t < 8; ++t) { M = fmaxf(M, v[t][0]); M = fmaxf(M, v[t][2]); }
            float S = 0.f;
            #pragma unroll
            for (int t = 0; t < 8; ++t) {
                S += v[t][1] * __expf(v[t][0] - M);
                S += v[t][3] * __expf(v[t][2] - M);
            }
            sOff[i] = fmaf(M, LOG2E, __log2f(S));
        }
    }
    asm volatile("s_waitcnt lgkmcnt(0)" ::: "memory");   // publish sOff
    __builtin_amdgcn_s_barrier();
    __builtin_amdgcn_sched_barrier(0);

    float4v acc[4][2];
    #pragma unroll
    for (int i = 0; i < 4; ++i)
        #pragma unroll
        for (int j = 0; j < 2; ++j) acc[i][j] = (float4v)0.f;
    float csa = 0.f;
    const int mrow = wjE * 16 + m16;

    // E phase body: nc = chunk, qA = sQA buffer, ro = row offset (0 / 64)
    #define EPHASE(nc, qA, ro)                                                    \
    {                                                                             \
        const int nbase = (nc) * 64 + wiE * 32 + quad * 4;                        \
        _Pragma("unroll")                                                         \
        for (int ti = 0; ti < 2; ++ti) {                                          \
            const int nl = (ro) + wiE * 32 + ti * 16 + m16;                       \
            const half8 an0 = *(const half8*)&(qA)[(size_t)nl * 64                \
                                                   + ((quad ^ (m16 & 7)) * 8)];   \
            const half8 an1 = *(const half8*)&(qA)[(size_t)nl * 64                \
                                                   + (((4 + quad) ^ (m16 & 7)) * 8)]; \
            float4v e = (float4v)0.f;                                             \
            e = __builtin_amdgcn_mfma_f32_16x16x32_f16(an0, bq[0], e, 0, 0, 0);   \
            e = __builtin_amdgcn_mfma_f32_16x16x32_f16(an1, bq[1], e, 0, 0, 0);   \
            const float4v o4 = *(const float4v*)&sOff[nbase + ti * 16];           \
            float c0 = 0.f; ushort4 pk;                                           \
            _Pragma("unroll")                                                     \
            for (int r = 0; r < 4; ++r) {                                         \
                const float p = __builtin_amdgcn_exp2f(fmaf(e[r], LOG2E, -o4[r]));\
                c0 += p; (&pk.x)[r] = f2bf(p);                                    \
            }                                                                     \
            csa += c0;                                                            \
            const int pc = (wiE * 4 + ti * 2 + (quad >> 1)) ^ (m16 & 7);          \
            *(ushort4*)&((unsigned short*)sP)[(size_t)mrow * 64 + pc * 8          \
                                              + (quad & 1) * 4] = pk;             \
        }                                                                         \
    }

    #define XRPHASE(xvr)                                                          \
    {                                                                             \
        _Pragma("unroll")                                                         \
        for (int ks = 0; ks < 2; ++ks) {                                          \
            short8 xa[4], pb[2];                                                  \
            _Pragma("unroll")                                                     \
            for (int ti = 0; ti < 4; ++ti)                                        \
                xa[ti] = *(const short8*)&(xvr)[(size_t)(wi * 64 + ti * 16 + m16) * 64 \
                                                + (((ks * 4 + quad) ^ (m16 & 7)) * 8)]; \
            _Pragma("unroll")                                                     \
            for (int tj = 0; tj < 2; ++tj)                                        \
                pb[tj] = *(const short8*)&sP[(size_t)(wj * 32 + tj * 16 + m16) * 64 \
                                             + (((ks * 4 + quad) ^ (m16 & 7)) * 8)]; \
            __builtin_amdgcn_s_setprio(1);                                        \
            _Pragma("unroll")                                                     \
            for (int ti = 0; ti < 4; ++ti)                                        \
                _Pragma("unroll")                                                 \
                for (int tj = 0; tj < 2; ++tj)                                    \
                    acc[ti][tj] = __builtin_amdgcn_mfma_f32_16x16x32_bf16(        \
                        xa[ti], pb[tj], acc[ti][tj], 0, 0, 0);                    \
            __builtin_amdgcn_s_setprio(0);                                        \
        }                                                                         \
    }

    for (int u = 0; u < 16; ++u) {
        half_t* xv0 = &sXV[(2 * u) % 3][0];
        half_t* xv1 = &sXV[(2 * u + 1) % 3][0];
        half_t* xv2 = &sXV[(2 * u + 2) % 3][0];
        const half_t* qA = &sQA[u & 1][0];

        // ---- even sub-chunk nc = 2u ----
        #pragma unroll
        for (int t = 0; t < 2; ++t) {           // stage chunk 2u+1 -> xv1
            const int g = t * 1024 + tid;
            const int r = g >> 3, c = g & 7;
            gload16(xvb + (size_t)r * Nn + (2 * u + 1) * 64 + ((c ^ (r & 7)) * 8),
                    xv1 + (size_t)g * 8);
        }
        if (u < 15) {                           // stage sQA rows (u+1)*128
            gload16(qb + (size_t)((u + 1) * 128 + sr) * 64 + qsw,
                    &sQA[(u + 1) & 1][(size_t)tid * 8]);
            asm volatile("s_waitcnt vmcnt(3)" ::: "memory");
        } else {
            asm volatile("s_waitcnt vmcnt(2)" ::: "memory");
        }
        __builtin_amdgcn_s_barrier();
        __builtin_amdgcn_sched_barrier(0);

        EPHASE(2 * u, qA, 0);
        asm volatile("s_waitcnt lgkmcnt(0)" ::: "memory");
        __builtin_amdgcn_s_barrier();
        __builtin_amdgcn_sched_barrier(0);
        XRPHASE(xv0);

        // ---- odd sub-chunk nc = 2u+1 ----
        if (u < 15) {
            #pragma unroll
            for (int t = 0; t < 2; ++t) {       // stage chunk 2u+2 -> xv2
                const int g = t * 1024 + tid;
                const int r = g >> 3, c = g & 7;
                gload16(xvb + (size_t)r * Nn + (2 * u + 2) * 64 + ((c ^ (r & 7)) * 8),
                        xv2 + (size_t)g * 8);
            }
            asm volatile("s_waitcnt vmcnt(2)" ::: "memory");
        } else {
            asm volatile("s_waitcnt vmcnt(0)" ::: "memory");
        }
        __builtin_amdgcn_s_barrier();
        __builtin_amdgcn_sched_barrier(0);

        EPHASE(2 * u + 1, qA, 64);
        asm volatile("s_waitcnt lgkmcnt(0)" ::: "memory");
        __builtin_amdgcn_s_barrier();
        __builtin_amdgcn_sched_barrier(0);
        XRPHASE(xv1);
    }
    #undef EPHASE
    #undef XRPHASE
    __syncthreads();   // all XR reads done before sP/sXV reuse

    // colsum reduce: quad butterfly, then cross-wiE via LDS (sP as floats)
    csa += __shfl_xor(csa, 16);
    csa += __shfl_xor(csa, 32);
    float* fb = (float*)sP;
    if (lane < 16) fb[wiE * 128 + wjE * 16 + lane] = csa;
    __syncthreads();
    float csr[2];
    #pragma unroll
    for (int tj = 0; tj < 2; ++tj) {
        const int m = wj * 32 + tj * 16 + m16;
        csr[tj] = 1.0f / (1e-9f + fb[m] + fb[128 + m]);
    }

    // d = h - xr*csr -> sD (fp16, swizzled [128 m][256 c], overlays sXV)
    const half_t* hb = h + (size_t)b * sNC;
    half_t* sD = &sXV[0][0];
    #pragma unroll
    for (int ti = 0; ti < 4; ++ti) {
        const int cg = wi * 64 + ti * 16 + quad * 4;
        const int cc = (cg >> 3) ^ (m16 & 7);      // swizzled 16B chunk
        const int sub = (quad & 1) * 4;
        #pragma unroll
        for (int tj = 0; tj < 2; ++tj) {
            const int mr = wj * 32 + tj * 16 + m16;
            const int mg = j0 + mr;
            const half4 hv = *(const half4*)&hb[(size_t)mg * Cc + cg];
            half4 o;
            #pragma unroll
            for (int r = 0; r < 4; ++r)
                o[r] = (half_t)((float)hv[r] - acc[ti][tj][r] * csr[tj]);
            *(half4*)&sD[(size_t)mr * 256 + cc * 8 + sub] = o;
        }
    }
    __syncthreads();   // sD complete (fb reads also done)

    // T phase: T[co][m] = sum_c tw[co][c] * d[m][c]; tw streamed from L2
    float4v acc2[4][2];
    #pragma unroll
    for (int i = 0; i < 4; ++i)
        #pragma unroll
        for (int j = 0; j < 2; ++j) acc2[i][j] = (float4v)0.f;
    #pragma unroll
    for (int ks = 0; ks < 8; ++ks) {
        half8 af[4], bf[2];
        #pragma unroll
        for (int tm = 0; tm < 4; ++tm)
            af[tm] = *(const half8*)&sD[(size_t)(wiT * 64 + tm * 16 + m16) * 256
                                        + (((ks * 4 + quad) ^ (m16 & 7)) * 8)];
        #pragma unroll
        for (int tc = 0; tc < 2; ++tc)
            bf[tc] = *(const half8*)&tw[(size_t)(wjT * 32 + tc * 16 + m16) * 256
                                        + ks * 32 + quad * 8];
        #pragma unroll
        for (int tm = 0; tm < 4; ++tm)
            #pragma unroll
            for (int tc = 0; tc < 2; ++tc)
                acc2[tm][tc] = __builtin_amdgcn_mfma_f32_16x16x32_f16(
                    af[tm], bf[tc], acc2[tm][tc], 0, 0, 0);
    }

    // epilogue: out = h + relu(bn(T + tb)); hNext fp16
    const long yB = (long)4 * Cc * Nn;
    float* yb = outL + (size_t)b * yB;
    half_t* hn = hNext ? hNext + (size_t)b * sNC : nullptr;
    #pragma unroll
    for (int tc = 0; tc < 2; ++tc) {
        const int co = wjT * 32 + tc * 16 + m16;
        const float tb2 = tb[co];
        const float sc2 = bng[co] * rsqrtf(bnv[co] + 1e-3f);
        const float sh2 = bnb[co] - bnm[co] * sc2;
        #pragma unroll
        for (int tm = 0; tm < 4; ++tm) {
            const int mg = j0 + wiT * 64 + tm * 16 + quad * 4;
            float4v o;
            #pragma unroll
            for (int r = 0; r < 4; ++r) {
                const float t2  = acc2[tm][tc][r] + tb2;
                const float rel = fmaxf(fmaf(t2, sc2, sh2), 0.f);
                const float hv  = (float)hb[(size_t)(mg + r) * Cc + co];
                const float ov  = hv + rel;
                o[r] = ov;
                if (hn) hn[(size_t)(mg + r) * Cc + co] = (half_t)ov;
            }
            *(float4v*)&yb[(size_t)co * Nn + mg] = o;
        }
    }
}

// x [B,C,N] fp32 -> xT [B,N,C] fp16
__global__ __launch_bounds__(256)
void xpose_cast(const float* __restrict__ x, half_t* __restrict__ xT)
{
    __shared__ half_t tile[32][33];
    const int tx = threadIdx.x & 31, ty = threadIdx.x >> 5;
    const int n0 = blockIdx.x * 32, c0 = blockIdx.y * 32, b = blockIdx.z;
    #pragma unroll
    for (int r = 0; r < 4; ++r)
        tile[ty * 4 + r][tx] =
            (half_t)x[((size_t)b * Cc + c0 + ty * 4 + r) * Nn + n0 + tx];
    __syncthreads();
    #pragma unroll
    for (int r = 0; r < 4; ++r)
        xT[((size_t)b * Nn + n0 + ty * 4 + r) * Cc + c0 + tx] = tile[tx][ty * 4 + r];
}

// single kernel casting all 5 weight tensors into one fp16 arena
__global__ __launch_bounds__(256)
void castall(const float* __restrict__ c1, const float* __restrict__ c2,
             const float* __restrict__ qk, const float* __restrict__ vw,
             const float* __restrict__ tw, half_t* __restrict__ dst)
{
    const int i = (blockIdx.x * 256 + threadIdx.x) * 4;   // grid 768 -> 786432 elems
    const float* s; int o;
    if      (i < 65536)  { s = c1; o = 0; }
    else if (i < 131072) { s = c2; o = 65536; }
    else if (i < 196608) { s = qk; o = 131072; }
    else if (i < 458752) { s = vw; o = 196608; }
    else                 { s = tw; o = 458752; }
    const float4v v = *(const float4v*)(s + (i - o));
    half4 out;
    #pragma unroll
    for (int r = 0; r < 4; ++r) out[r] = (half_t)v[r];
    *(half4*)(dst + i) = out;
}

extern "C" void kernel_launch(void* const* d_in, const int* in_sizes, int n_in,
                              void* d_out, int out_size, void* d_ws, size_t ws_size,
                              hipStream_t stream)
{
    const float* x    = (const float*)d_in[0];
    const float* c1w  = (const float*)d_in[1];
    const float* c2w  = (const float*)d_in[2];
    const float* bn1g = (const float*)d_in[3], *bn1b = (const float*)d_in[4];
    const float* bn1m = (const float*)d_in[5], *bn1v = (const float*)d_in[6];
    const float* bn2g = (const float*)d_in[7], *bn2b = (const float*)d_in[8];
    const float* bn2m = (const float*)d_in[9], *bn2v = (const float*)d_in[10];
    const float* qkw  = (const float*)d_in[11];
    const float* vw   = (const float*)d_in[12];
    const float* vb   = (const float*)d_in[13];
    const float* tw   = (const float*)d_in[14];
    const float* tb   = (const float*)d_in[15];
    const float* sag  = (const float*)d_in[16];
    const float* sab  = (const float*)d_in[17];
    const float* sam  = (const float*)d_in[18];
    const float* sav  = (const float*)d_in[19];
    float* out = (float*)d_out;

    // ---- workspace layout ----
    char* ws = (char*)d_ws;
    const size_t HSZ = (size_t)Bn * Nn * Cc * 2;          // 16 MB
    half_t* xT   = (half_t*)(ws);
    half_t* hA   = (half_t*)(ws + HSZ);
    half_t* hBuf = (half_t*)(ws + 2 * HSZ);
    half_t* q_s  = (half_t*)(ws + 3 * HSZ);               // 4 MB
    half_t* xv_s = (half_t*)(ws + 3 * HSZ + (size_t)4194304);       // 16 MB (bf16)
    float*  Pbuf = (float*) (ws + 4 * HSZ + (size_t)4194304);       // 4 MB
    half_t* warena = (half_t*)(ws + 4 * HSZ + (size_t)8388608);     // 1.5 MB
    half_t* wc1  = warena;
    half_t* wc2  = wc1 + 65536;
    half_t* wqk  = wc2 + 65536;
    half_t* wv   = wqk + 65536;
    half_t* wt   = wv  + 262144;

    dim3 blk(256);

    castall<<<768, blk, 0, stream>>>(c1w, c2w, qkw, vw, tw, warena);
    xpose_cast<<<dim3(Nn / 32, Cc / 32, Bn), blk, 0, stream>>>(x, xT);

    mgemm<EPI_H, 256, 128, 4, 2, false><<<dim3(16, 1, Bn), dim3(512), 0, stream>>>(
        wc1, 0, xT, sNC, hA, sNC, Cc,
        nullptr, bn1g, bn1b, bn1m, bn1v, Cc);
    mgemm<EPI_H, 256, 128, 4, 2, false><<<dim3(16, 1, Bn), dim3(512), 0, stream>>>(
        wc2, 0, hA, sNC, hBuf, sNC, Cc,
        nullptr, bn2g, bn2b, bn2m, bn2v, Cc);

    half_t* hcur = hBuf;
    half_t* hnxt = hA;
    for (int L = 0; L < 4; ++L) {
        mgemm<EPI_RAW, 64, 256, 1, 4, false><<<dim3(8, 1, Bn), blk, 0, stream>>>(
            wqk + (long)L * C4 * Cc, 0, hcur, sNC, q_s, sNQ, C4,
            nullptr, nullptr, nullptr, nullptr, nullptr, Cc);
        estats<<<dim3(16, 16, Bn), blk, 0, stream>>>(q_s, Pbuf);
        mgemm<EPI_XV, 128, 256, 2, 4, true><<<dim3(1, 16, Bn), dim3(512), 0, stream>>>(
            hcur, sNC, wv + (long)L * Cc * Cc, 0, xv_s, (long)Cc * Nn, Nn,
            vb + L * Cc, nullptr, nullptr, nullptr, nullptr, Cc);
        flashxr<<<dim3(256), dim3(1024), 0, stream>>>(
            q_s, xv_s, hcur, Pbuf,
            wt + (long)L * Cc * Cc, tb + L * Cc,
            sag + L * Cc, sab + L * Cc, sam + L * Cc, sav + L * Cc,
            out + (long)L * Cc * Nn, (L < 3) ? hnxt : nullptr);
        half_t* tmp = hcur; hcur = hnxt; hnxt = tmp;
    }
}